// Round 8
// baseline (3905.482 us; speedup 1.0000x reference)
//
#include <hip/hip_runtime.h>
#include <math.h>

// 2-layer LSTM (B=1024,T=512,F=64,H=128) + FC head.
// R13: TWO PHASE-SHIFTED TILES PER BLOCK. Evidence: R9/R10 step ~3600cyc vs
// ~800cyc of pipe work -> lockstep phase alignment leaves pipes idle. Batch
// rows are independent recurrences, so each block now runs two 16-row tiles
// (A,B) half a step apart: every barrier phase = [T1: 16 h-MFMA + 24 x-MFMA]
// || [T2: gates VALU/trans + staging + h1c store] in the SAME waves -> one
// tile's MFMA issue fills the other tile's transcendental-chain stalls.
// 32 producer + 32 consumer blocks (512 thr, fat waves, all operands
// LDS-staged coalesced as R9/R10 -- R11/R12's direct-global scatter loads
// were the regression and are gone). One flag per block-pair = min(A,B)
// h1c progress; producer never waits on consumer; polls bounded.
// Math/accumulation order identical to R9-R12: absmax 1.22e-4.

#define BB 1024
#define TT 512
#define FF 64
#define HH 128
#define LOG2E 1.44269504088896340736f
#define TWOLOG2E 2.88539008177792681472f

typedef __attribute__((ext_vector_type(8))) short     v8s;  // 8 x bf16
typedef __attribute__((ext_vector_type(8))) _Float16  v8h;  // 8 x fp16
typedef __attribute__((ext_vector_type(4))) float     v4f;

__device__ __forceinline__ short bf16r(float v) {  // RNE fp32->bf16
    unsigned u = __float_as_uint(v);
    return (short)((u + 0x7FFFu + ((u >> 16) & 1u)) >> 16);
}
__device__ __forceinline__ float bf16tof(short s) {
    return __uint_as_float(((unsigned)(unsigned short)s) << 16);
}
// rcp(1 + exp2(y)) : core of exp2-domain sigmoid/tanh.
__device__ __forceinline__ float rcp1p(float y) {
    return __builtin_amdgcn_rcpf(1.0f + __builtin_exp2f(y));
}
__device__ __forceinline__ void light_barrier() {
    asm volatile("s_waitcnt lgkmcnt(0)\n\ts_barrier" ::: "memory");
}
__device__ __forceinline__ void heavy_barrier() {
    asm volatile("s_waitcnt vmcnt(0) lgkmcnt(0)\n\ts_barrier" ::: "memory");
}
__device__ __forceinline__ void wait_flag_ge(int* f, int need) {
    for (int i = 0; i < 4000000; ++i) {
        int v = __hip_atomic_fetch_add(f, 0, __ATOMIC_ACQUIRE,
                                       __HIP_MEMORY_SCOPE_AGENT);
        if (v >= need) return;
        __builtin_amdgcn_s_sleep(4);
    }
}
// Truncation-based hi/lo bf16 split of two floats, packed into 2 u32.
__device__ __forceinline__ void split2(float a, float b,
                                       unsigned& hi, unsigned& lo) {
    unsigned ua = __float_as_uint(a), ub = __float_as_uint(b);
    hi = (ua >> 16) | (ub & 0xFFFF0000u);
    float ra = a - __uint_as_float(ua & 0xFFFF0000u);
    float rb = b - __uint_as_float(ub & 0xFFFF0000u);
    lo = (__float_as_uint(ra) >> 16) | (__float_as_uint(rb) & 0xFFFF0000u);
}

// MFMA 16x16x32 layouts: A/B: m(n)=lane&15, k=(lane>>4)*8+j ; C/D: col=lane&15,
// row=(lane>>4)*4+r.

// ======================= producer phase macros =======================
// h-MFMA(t) for tile T: init from xacc(t), accumulate Whh*h(t-1) -> gacT.
#define P_HMFMA(T, HBR)                                                        \
  { v8h ah[4];                                                                 \
    _Pragma("unroll") for (int q = 0; q < 4; ++q)                              \
      ah[q] = *(const v8h*)&hbuf##T[HBR][lane16*136 + q*32 + quad*8];          \
    v4f g0 = xacc##T[0], g1 = xacc##T[1], g2 = xacc##T[2], g3 = xacc##T[3];    \
    _Pragma("unroll") for (int q = 0; q < 4; ++q) {                            \
      g0 = __builtin_amdgcn_mfma_f32_16x16x32_f16(ah[q], bh[0][q], g0,0,0,0);  \
      g1 = __builtin_amdgcn_mfma_f32_16x16x32_f16(ah[q], bh[1][q], g1,0,0,0);  \
      g2 = __builtin_amdgcn_mfma_f32_16x16x32_f16(ah[q], bh[2][q], g2,0,0,0);  \
      g3 = __builtin_amdgcn_mfma_f32_16x16x32_f16(ah[q], bh[3][q], g3,0,0,0);  \
    }                                                                          \
    gac##T[0]=g0; gac##T[1]=g1; gac##T[2]=g2; gac##T[3]=g3; }

// xacc(next) = bias + Wih0*x(next) from poolT[PLR] (split-bf16).
#define P_XMFMA(T, PLR)                                                        \
  { v8s xh[2], xl[2];                                                          \
    _Pragma("unroll") for (int q = 0; q < 2; ++q) {                            \
      xh[q] = *(const v8s*)&pool##T[PLR][0][lane16*72 + q*32 + quad*8];        \
      xl[q] = *(const v8s*)&pool##T[PLR][1][lane16*72 + q*32 + quad*8];        \
    }                                                                          \
    _Pragma("unroll") for (int g = 0; g < 4; ++g) {                            \
      v4f a = {bias[g], bias[g], bias[g], bias[g]};                            \
      a = __builtin_amdgcn_mfma_f32_16x16x32_bf16(xh[0], bxh[g][0], a,0,0,0);  \
      a = __builtin_amdgcn_mfma_f32_16x16x32_bf16(xh[0], bxl[g][0], a,0,0,0);  \
      a = __builtin_amdgcn_mfma_f32_16x16x32_bf16(xl[0], bxh[g][0], a,0,0,0);  \
      a = __builtin_amdgcn_mfma_f32_16x16x32_bf16(xh[1], bxh[g][1], a,0,0,0);  \
      a = __builtin_amdgcn_mfma_f32_16x16x32_bf16(xh[1], bxl[g][1], a,0,0,0);  \
      a = __builtin_amdgcn_mfma_f32_16x16x32_bf16(xl[1], bxh[g][1], a,0,0,0);  \
      xacc##T[g] = a; } }

#define P_MFMA(T, HBR, PLR)  { P_HMFMA(T, HBR); P_XMFMA(T, PLR); }

// stage x(tl) into poolT[PLW] from xregT, then prefetch next into xregT.
#define P_STAGE(T, PLW, tl_)                                                   \
  { unsigned hi_, lo_; split2(xreg##T.x, xreg##T.y, hi_, lo_);                 \
    *(unsigned*)&pool##T[PLW][0][xr_row*72 + xr_col] = hi_;                    \
    *(unsigned*)&pool##T[PLW][1][xr_row*72 + xr_col] = lo_;                    \
    { long t_ = (tl_) < TT ? (long)(tl_) : (long)(TT-1);                       \
      xreg##T = *(const float2*)(xrow##T + t_*FF); } }

#define GATES_CORE(T, HBW)                                                     \
  _Pragma("unroll") for (int r = 0; r < 4; ++r) {                              \
    float ig = rcp1p(-gac##T[0][r]);                                           \
    float fg = rcp1p(-gac##T[1][r]);                                           \
    float gt = fmaf(-2.0f, rcp1p(gac##T[2][r]), 1.0f);                         \
    float og = rcp1p(-gac##T[3][r]);                                           \
    c##T[r] = fmaf(fg, c##T[r], ig * gt);                                      \
    float th = fmaf(-2.0f, rcp1p(TWOLOG2E * c##T[r]), 1.0f);                   \
    hbuf##T[HBW][(quad*4 + r)*136 + jh] = (_Float16)(og * th);                 \
  }

// producer gates phase, step tv: coop h1c store of h(tv-1), gates, staging.
#define P_GATES(T, HBW, HBR, PLW, tv)                                          \
  { if ((tv) > 0) {                                                            \
      uint2 hv = *(const uint2*)&hbuf##T[HBR][hr_row*136 + hr_col];            \
      *(uint2*)hcs##T = hv; hcs##T += (long)BB*HH; }                           \
    GATES_CORE(T, HBW);                                                        \
    P_STAGE(T, PLW, (tv)+3); }

// ======================= consumer phase macros =======================
#define C_HMFMA(T, HBR)                                                        \
  { v8h ah[4];                                                                 \
    _Pragma("unroll") for (int q = 0; q < 4; ++q)                              \
      ah[q] = *(const v8h*)&hbuf##T[HBR][lane16*136 + q*32 + quad*8];          \
    v4f g0 = a1acc##T[0], g1 = a1acc##T[1], g2 = a1acc##T[2], g3 = a1acc##T[3];\
    _Pragma("unroll") for (int q = 0; q < 4; ++q) {                            \
      g0 = __builtin_amdgcn_mfma_f32_16x16x32_f16(ah[q], bh[0][q], g0,0,0,0);  \
      g1 = __builtin_amdgcn_mfma_f32_16x16x32_f16(ah[q], bh[1][q], g1,0,0,0);  \
      g2 = __builtin_amdgcn_mfma_f32_16x16x32_f16(ah[q], bh[2][q], g2,0,0,0);  \
      g3 = __builtin_amdgcn_mfma_f32_16x16x32_f16(ah[q], bh[3][q], g3,0,0,0);  \
    }                                                                          \
    gac##T[0]=g0; gac##T[1]=g1; gac##T[2]=g2; gac##T[3]=g3; }

#define C_A1MFMA(T, SBR)                                                       \
  { v8h a1[4];                                                                 \
    _Pragma("unroll") for (int q = 0; q < 4; ++q)                              \
      a1[q] = *(const v8h*)&sb##T[(SBR)*2176 + lane16*136 + q*32 + quad*8];    \
    _Pragma("unroll") for (int g = 0; g < 4; ++g) {                            \
      v4f a = {bias[g], bias[g], bias[g], bias[g]};                            \
      _Pragma("unroll") for (int q = 0; q < 4; ++q)                            \
        a = __builtin_amdgcn_mfma_f32_16x16x32_f16(a1[q], bi[g][q], a,0,0,0);  \
      a1acc##T[g] = a; } }

#define C_GATES_CORE(T, HBW, tv, LAST)                                         \
  _Pragma("unroll") for (int r = 0; r < 4; ++r) {                              \
    float ig = rcp1p(-gac##T[0][r]);                                           \
    float fg = rcp1p(-gac##T[1][r]);                                           \
    float gt = fmaf(-2.0f, rcp1p(gac##T[2][r]), 1.0f);                         \
    float og = rcp1p(-gac##T[3][r]);                                           \
    c##T[r] = fmaf(fg, c##T[r], ig * gt);                                      \
    float th = fmaf(-2.0f, rcp1p(TWOLOG2E * c##T[r]), 1.0f);                   \
    float h = og * th;                                                         \
    hbuf##T[HBW][(quad*4 + r)*136 + jh] = (_Float16)h;                         \
    if (LAST) hs[(b0##T + quad*4 + r)*HH + jh] = h;                            \
  }

// consumer gates phase, step tv: gates, a1acc(tv+1), h1 staging + prefetch.
#define C_GATES(T, HBW, SBR, SBW, tv, LAST)                                    \
  { C_GATES_CORE(T, HBW, tv, LAST);                                            \
    C_A1MFMA(T, SBR);                                                          \
    *(uint2*)&sb##T[(SBW)*2176 + hr_row*136 + hr_col] = hreg##T;               \
    { long t_ = (tv)+3 < TT ? (long)((tv)+3) : (long)(TT-1);                   \
      hreg##T = *(const uint2*)(hrow##T + t_*(long)BB*HH); } }

__global__ __launch_bounds__(512, 1) void fused_lstm_kernel(
    const float* __restrict__ x,
    const float* __restrict__ Wih0, const float* __restrict__ Whh0,
    const float* __restrict__ bih0, const float* __restrict__ bhh0,
    const float* __restrict__ Wih1, const float* __restrict__ Whh1,
    const float* __restrict__ bih1, const float* __restrict__ bhh1,
    _Float16* __restrict__ h1c, float* __restrict__ hs, int* __restrict__ flags)
{
    const int tid = threadIdx.x;
    const int l = tid & 63;
    const int lane16 = l & 15;
    const int quad = l >> 4;
    const int jh = 16 * (tid >> 6) + lane16;
    const int hr_row = tid >> 5;        // 0..15 coop rows
    const int hr_col = (tid & 31) * 4;  // 0..124 (x4 halves)
    const int xr_row = tid >> 5;
    const int xr_col = (tid & 31) * 2;

    __shared__ __align__(16) _Float16 hbufA[2][2176], hbufB[2][2176]; // 17.4KB
    __shared__ __align__(16) short poolA[2][2][1152], poolB[2][2][1152]; // 18.4KB

    if (blockIdx.x < 32) {
        // ================= LAYER 0 (producer), tiles 2k, 2k+1 ==============
        const int k = blockIdx.x;
        const long b0A = (long)k * 32, b0B = b0A + 16;
        int* flagp = &flags[k];

        v8h bh[4][4]; v8s bxh[4][2], bxl[4][2]; float bias[4];
#pragma unroll
        for (int g = 0; g < 4; ++g) {
            const int col = g * 128 + jh;
            const float sg = (g == 2) ? TWOLOG2E : LOG2E;
            bias[g] = (bih0[col] + bhh0[col]) * sg;
#pragma unroll
            for (int q = 0; q < 4; ++q) {
                const float* p = &Whh0[(long)col * HH + q * 32 + quad * 8];
                float4 u0 = *(const float4*)p;
                float4 u1 = *(const float4*)(p + 4);
                v8h t;
                t[0]=(_Float16)(u0.x*sg); t[1]=(_Float16)(u0.y*sg);
                t[2]=(_Float16)(u0.z*sg); t[3]=(_Float16)(u0.w*sg);
                t[4]=(_Float16)(u1.x*sg); t[5]=(_Float16)(u1.y*sg);
                t[6]=(_Float16)(u1.z*sg); t[7]=(_Float16)(u1.w*sg);
                bh[g][q] = t;
            }
#pragma unroll
            for (int q = 0; q < 2; ++q) {
                const float* p = &Wih0[(long)col * FF + q * 32 + quad * 8];
                float4 u0 = *(const float4*)p;
                float4 u1 = *(const float4*)(p + 4);
                float vv[8] = {u0.x,u0.y,u0.z,u0.w,u1.x,u1.y,u1.z,u1.w};
                v8s hi, lo;
#pragma unroll
                for (int e = 0; e < 8; ++e) {
                    float vs = vv[e] * sg;
                    short hb = bf16r(vs);
                    hi[e] = hb;
                    lo[e] = bf16r(vs - bf16tof(hb));
                }
                bxh[g][q] = hi; bxl[g][q] = lo;
            }
        }
        for (int i = tid; i < 2176; i += 512) {
            hbufA[0][i] = (_Float16)0.0f; hbufB[0][i] = (_Float16)0.0f;
        }
        const float* xrowA = x + (b0A + xr_row) * (long)TT * FF + xr_col;
        const float* xrowB = x + (b0B + xr_row) * (long)TT * FF + xr_col;
        {   // stage x(0) both tiles
            float2 v0 = *(const float2*)xrowA;
            unsigned hi, lo; split2(v0.x, v0.y, hi, lo);
            *(unsigned*)&poolA[0][0][xr_row*72 + xr_col] = hi;
            *(unsigned*)&poolA[0][1][xr_row*72 + xr_col] = lo;
            float2 w0 = *(const float2*)xrowB;
            split2(w0.x, w0.y, hi, lo);
            *(unsigned*)&poolB[0][0][xr_row*72 + xr_col] = hi;
            *(unsigned*)&poolB[0][1][xr_row*72 + xr_col] = lo;
        }
        __syncthreads();

        v4f xaccA[4], xaccB[4], gacA[4], gacB[4];
        float cA[4] = {0,0,0,0}, cB[4] = {0,0,0,0};
        P_XMFMA(A, 0);               // xaccA(0)
        P_XMFMA(B, 0);               // xaccB(0)
        {   // stage x(1)
            float2 v1 = *(const float2*)(xrowA + FF);
            unsigned hi, lo; split2(v1.x, v1.y, hi, lo);
            *(unsigned*)&poolA[1][0][xr_row*72 + xr_col] = hi;
            *(unsigned*)&poolA[1][1][xr_row*72 + xr_col] = lo;
            float2 w1 = *(const float2*)(xrowB + FF);
            split2(w1.x, w1.y, hi, lo);
            *(unsigned*)&poolB[1][0][xr_row*72 + xr_col] = hi;
            *(unsigned*)&poolB[1][1][xr_row*72 + xr_col] = lo;
        }
        float2 xregA = *(const float2*)(xrowA + 2*FF);
        float2 xregB = *(const float2*)(xrowB + 2*FF);
        light_barrier();

        _Float16* hcsA = h1c + (b0A + hr_row) * HH + hr_col;
        _Float16* hcsB = h1c + (b0B + hr_row) * HH + hr_col;

        for (int tp = 0; tp < TT/2; ++tp) {
            // phase 1: A-MFMA(2tp) || B-gates(2tp-1)
            P_MFMA(A, 0, 1);
            if (tp > 0) { P_GATES(B, 0, 1, 1, 2*tp - 1); }
            light_barrier();
            // phase 2: B-MFMA(2tp) || A-gates(2tp)
            P_MFMA(B, 0, 1);
            P_GATES(A, 1, 0, 0, 2*tp);
            light_barrier();
            // phase 3: A-MFMA(2tp+1) || B-gates(2tp)
            P_MFMA(A, 1, 0);
            P_GATES(B, 1, 0, 0, 2*tp);
            light_barrier();
            // phase 4: B-MFMA(2tp+1) || A-gates(2tp+1)
            P_MFMA(B, 1, 0);
            P_GATES(A, 0, 1, 1, 2*tp + 1);
            if ((tp & 3) == 3) {
                heavy_barrier();   // drains all waves' h1c stores
                if (tid == 0)
                    __hip_atomic_store(flagp, 2*tp, __ATOMIC_RELEASE,
                                       __HIP_MEMORY_SCOPE_AGENT);
            } else {
                light_barrier();
            }
        }
        // tail: B-gates(TT-1)
        P_GATES(B, 0, 1, 1, TT - 1);
        light_barrier();
        {   // coop-store h(TT-1) of both tiles (both live in slot 0)
            uint2 va = *(const uint2*)&hbufA[0][hr_row*136 + hr_col];
            *(uint2*)hcsA = va;
            uint2 vb = *(const uint2*)&hbufB[0][hr_row*136 + hr_col];
            *(uint2*)hcsB = vb;
        }
        heavy_barrier();
        if (tid == 0)
            __hip_atomic_store(flagp, TT, __ATOMIC_RELEASE,
                               __HIP_MEMORY_SCOPE_AGENT);
    } else {
        // ================= LAYER 1 (consumer), tiles 2k, 2k+1 ==============
        const int k = blockIdx.x - 32;
        const long b0A = (long)k * 32, b0B = b0A + 16;
        int* flagp = &flags[k];

        v8h bi[4][4], bh[4][4]; float bias[4];
#pragma unroll
        for (int g = 0; g < 4; ++g) {
            const int col = g * 128 + jh;
            const float sg = (g == 2) ? TWOLOG2E : LOG2E;
            bias[g] = (bih1[col] + bhh1[col]) * sg;
#pragma unroll
            for (int q = 0; q < 4; ++q) {
                const float* pi = &Wih1[(long)col * HH + q * 32 + quad * 8];
                float4 u0 = *(const float4*)pi;
                float4 u1 = *(const float4*)(pi + 4);
                v8h t;
                t[0]=(_Float16)(u0.x*sg); t[1]=(_Float16)(u0.y*sg);
                t[2]=(_Float16)(u0.z*sg); t[3]=(_Float16)(u0.w*sg);
                t[4]=(_Float16)(u1.x*sg); t[5]=(_Float16)(u1.y*sg);
                t[6]=(_Float16)(u1.z*sg); t[7]=(_Float16)(u1.w*sg);
                bi[g][q] = t;
                const float* ph = &Whh1[(long)col * HH + q * 32 + quad * 8];
                float4 v0 = *(const float4*)ph;
                float4 v1 = *(const float4*)(ph + 4);
                v8h s;
                s[0]=(_Float16)(v0.x*sg); s[1]=(_Float16)(v0.y*sg);
                s[2]=(_Float16)(v0.z*sg); s[3]=(_Float16)(v0.w*sg);
                s[4]=(_Float16)(v1.x*sg); s[5]=(_Float16)(v1.y*sg);
                s[6]=(_Float16)(v1.z*sg); s[7]=(_Float16)(v1.w*sg);
                bh[g][q] = s;
            }
        }
        for (int i = tid; i < 2176; i += 512) {
            hbufA[0][i] = (_Float16)0.0f; hbufB[0][i] = (_Float16)0.0f;
        }
        _Float16* sbA = (_Float16*)poolA;   // 2 slots, stride 2176 halves
        _Float16* sbB = (_Float16*)poolB;
        const _Float16* hrowA = h1c + (b0A + hr_row) * HH + hr_col;
        const _Float16* hrowB = h1c + (b0B + hr_row) * HH + hr_col;

        if (tid == 0) wait_flag_ge(flagp, 14);
        __syncthreads();

        v4f a1accA[4], a1accB[4], gacA[4], gacB[4];
        float cA[4] = {0,0,0,0}, cB[4] = {0,0,0,0};
        uint2 hregA, hregB;
        {   // stage h1(0) of both tiles
            uint2 ha = *(const uint2*)hrowA;
            *(uint2*)&sbA[0*2176 + hr_row*136 + hr_col] = ha;
            uint2 hb = *(const uint2*)hrowB;
            *(uint2*)&sbB[0*2176 + hr_row*136 + hr_col] = hb;
        }
        light_barrier();
        C_A1MFMA(A, 0);              // a1accA(0)
        C_A1MFMA(B, 0);              // a1accB(0)
        {   // stage h1(1); prefetch h1(2)
            uint2 ha = *(const uint2*)(hrowA + (long)BB*HH);
            *(uint2*)&sbA[1*2176 + hr_row*136 + hr_col] = ha;
            uint2 hb = *(const uint2*)(hrowB + (long)BB*HH);
            *(uint2*)&sbB[1*2176 + hr_row*136 + hr_col] = hb;
            hregA = *(const uint2*)(hrowA + 2L*BB*HH);
            hregB = *(const uint2*)(hrowB + 2L*BB*HH);
        }
        light_barrier();

        for (int tp = 0; tp < TT/2; ++tp) {
            if ((tp & 3) == 0 && tp > 0) {
                if (tid == 0)
                    wait_flag_ge(flagp, (2*tp + 11 < TT) ? 2*tp + 11 : TT);
                light_barrier();
            }
            // phase 1: A-MFMA(2tp) || B-gates(2tp-1)
            C_HMFMA(A, 0);
            if (tp > 0) { C_GATES(B, 0, 0, 1, 2*tp - 1, false); }
            light_barrier();
            // phase 2: B-MFMA(2tp) || A-gates(2tp)
            C_HMFMA(B, 0);
            C_GATES(A, 1, 1, 0, 2*tp, false);
            light_barrier();
            // phase 3: A-MFMA(2tp+1) || B-gates(2tp)
            C_HMFMA(A, 1);
            C_GATES(B, 1, 1, 0, 2*tp, false);
            light_barrier();
            // phase 4: B-MFMA(2tp+1) || A-gates(2tp+1)
            C_HMFMA(B, 1);
            C_GATES(A, 0, 0, 1, 2*tp + 1, (2*tp + 1) == TT - 1);
            light_barrier();
        }
        // tail: B-gates(TT-1) with hs store
        C_GATES(B, 0, 0, 1, TT - 1, true);
    }
}

// ---------------- FC head: out = relu(h @ fc1^T + b1) @ fc2^T + b2 ----------
__global__ __launch_bounds__(64) void head_kernel(
    const float* __restrict__ h, const float* __restrict__ w1,
    const float* __restrict__ b1, const float* __restrict__ w2,
    const float* __restrict__ b2, float* __restrict__ out)
{
    const int b = blockIdx.x;
    const int n = threadIdx.x;
    float acc = b1[n];
#pragma unroll
    for (int k = 0; k < HH; ++k)
        acc = fmaf(w1[n * HH + k], h[b * HH + k], acc);
    float v = fmaxf(acc, 0.0f) * w2[n];
#pragma unroll
    for (int off = 32; off > 0; off >>= 1)
        v += __shfl_down(v, off);
    if (n == 0) out[b] = v + b2[0];
}

extern "C" void kernel_launch(void* const* d_in, const int* in_sizes, int n_in,
                              void* d_out, int out_size, void* d_ws, size_t ws_size,
                              hipStream_t stream)
{
    const float* x    = (const float*)d_in[0];
    const float* Wih0 = (const float*)d_in[1];
    const float* Whh0 = (const float*)d_in[2];
    const float* bih0 = (const float*)d_in[3];
    const float* bhh0 = (const float*)d_in[4];
    const float* Wih1 = (const float*)d_in[5];
    const float* Whh1 = (const float*)d_in[6];
    const float* bih1 = (const float*)d_in[7];
    const float* bhh1 = (const float*)d_in[8];
    const float* w1   = (const float*)d_in[9];
    const float* b1   = (const float*)d_in[10];
    const float* w2   = (const float*)d_in[11];
    const float* b2   = (const float*)d_in[12];
    float* out = (float*)d_out;

    char* ws = (char*)d_ws;
    _Float16* h1c = (_Float16*)ws;                              // 134 MB, [t][B][H]
    float* hs  = (float*)(ws + (size_t)BB * TT * HH * sizeof(_Float16));
    int* flags = (int*)(ws + (size_t)BB * TT * HH * sizeof(_Float16)
                           + (size_t)BB * HH * sizeof(float));

    hipMemsetAsync(flags, 0, 32 * sizeof(int), stream);

    fused_lstm_kernel<<<64, 512, 0, stream>>>(
        x, Wih0, Whh0, bih0, bhh0, Wih1, Whh1, bih1, bhh1, h1c, hs, flags);
    head_kernel<<<BB, 64, 0, stream>>>(hs, w1, b1, w2, b2, out);
}